// Round 9
// baseline (116.713 us; speedup 1.0000x reference)
//
#include <hip/hip_runtime.h>

#define NNODES 2048
#define NHEAD 8
#define DKDIM 64

typedef unsigned int uint;
typedef unsigned short ushort;
typedef unsigned char uchar;
typedef __fp16 h2 __attribute__((ext_vector_type(2)));
typedef __fp16 h8 __attribute__((ext_vector_type(8)));
typedef float f4 __attribute__((ext_vector_type(4)));

#define KSCALE 0.18033688011112042f   // 0.125 * log2(e)
#define CLAMP2 14.426950408889634f    // 10 * log2(e)

__device__ __forceinline__ uint pk2(float a, float b) {
    union { h2 h; uint u; } x; x.h = __builtin_amdgcn_cvt_pkrtz(a, b); return x.u;
}

// ---- k -> fp16 [head][node][dim], pre-scaled, 16B-blocks XOR-swizzled by (node&7) ----
__global__ void conv_k(const float* __restrict__ k, uint4* __restrict__ kc) {
    int o = blockIdx.x * 256 + threadIdx.x;   // 16B out-block id, 0..131071
    int row = o >> 3;                          // h*2048 + node
    int node = row & 2047;
    int h = row >> 11;
    int b_in = (o & 7) ^ (node & 7);
    const float* src = k + ((size_t)node * 512 + h * 64 + b_in * 8);
    float4 f0 = *(const float4*)src;
    float4 f1 = *(const float4*)(src + 4);
    uint4 out;
    out.x = pk2(f0.x * KSCALE, f0.y * KSCALE);
    out.y = pk2(f0.z * KSCALE, f0.w * KSCALE);
    out.z = pk2(f1.x * KSCALE, f1.y * KSCALE);
    out.w = pk2(f1.z * KSCALE, f1.w * KSCALE);
    kc[o] = out;
}

// ---- v -> fp16 transposed [head][dim][node], 16B-blocks XOR-swizzled by (dim&7) within each 128B segment ----
__global__ void conv_vT(const float* __restrict__ v, ushort* __restrict__ vt) {
    __shared__ float tile[64][65];
    int b = blockIdx.x;        // 256 = 8 heads * 32 node-tiles
    int h = b & 7, tn = b >> 3;
    int t = threadIdx.x;
    int nl = t >> 2, dq = (t & 3) * 16;
    const float* src = v + ((size_t)(tn * 64 + nl) * 512 + h * 64 + dq);
#pragma unroll
    for (int i = 0; i < 4; ++i) {
        float4 f = *(const float4*)(src + i * 4);
        tile[nl][dq + i * 4 + 0] = f.x;
        tile[nl][dq + i * 4 + 1] = f.y;
        tile[nl][dq + i * 4 + 2] = f.z;
        tile[nl][dq + i * 4 + 3] = f.w;
    }
    __syncthreads();
    int dim = t >> 2, nq = (t & 3) * 16;
    uint wv[8];
#pragma unroll
    for (int i = 0; i < 8; ++i)
        wv[i] = pk2(tile[nq + 2 * i][dim], tile[nq + 2 * i + 1][dim]);
    int swz = dim & 7;
    int nb0 = (t & 3) * 2;
    char* base = (char*)vt + ((size_t)(h * 64 + dim) * 2048 + tn * 64) * 2;
    uint4 lo = { wv[0], wv[1], wv[2], wv[3] };
    uint4 hi = { wv[4], wv[5], wv[6], wv[7] };
    *(uint4*)(base + ((nb0 ^ swz) * 16)) = lo;
    *(uint4*)(base + (((nb0 + 1) ^ swz) * 16)) = hi;
}

// ---- multiplicity matrix A^T[src][dst] u8, built with packed-byte atomics ----
__global__ void histA(const int* __restrict__ es, const int* __restrict__ ed,
                      uint* __restrict__ A32) {
    int i = blockIdx.x * 256 + threadIdx.x;
    uint idx = (uint)es[i] * 2048u + (uint)ed[i];
    atomicAdd(&A32[idx >> 2], 1u << ((idx & 3) * 8));
}

// ---- dense masked attention: block = 64 dst rows x 1 head, 4 waves x 16 rows ----
__global__ void __launch_bounds__(256) attn_kernel(
    const float* __restrict__ q, const ushort* __restrict__ kc, const ushort* __restrict__ vt,
    const uchar* __restrict__ A8, float* __restrict__ out) {
    __shared__ char Kb[2][8192];   // [64 src][128B], swizzled
    __shared__ char Vb[2][8192];   // [64 dim][128B], swizzled
    __shared__ char Sb[4 * 2304];  // per-wave S: [16 dst][144B]

    int b = blockIdx.x;
    int h = b & 7;
    int dst0 = (b >> 3) * 64;
    int t = threadIdx.x, w = t >> 6, l = t & 63, c = l & 15, g = l >> 4;

    const char* kH = (const char*)kc + (size_t)h * 262144;
    const char* vH = (const char*)vt + (size_t)h * 262144;
    char* Sw = Sb + w * 2304;

    // Q fragments (fp32 -> fp16 in-register); A-frag: m=c, k = ch*32 + 8g + i
    h8 qf[2];
    {
        size_t qb = (size_t)(dst0 + w * 16 + c) * 512 + h * 64 + g * 8;
#pragma unroll
        for (int ch = 0; ch < 2; ++ch) {
            float4 f0 = *(const float4*)(q + qb + ch * 32);
            float4 f1 = *(const float4*)(q + qb + ch * 32 + 4);
            union { uint u[4]; h8 v; } U;
            U.u[0] = pk2(f0.x, f0.y);
            U.u[1] = pk2(f0.z, f0.w);
            U.u[2] = pk2(f1.x, f1.y);
            U.u[3] = pk2(f1.z, f1.w);
            qf[ch] = U.v;
        }
    }

    f4 acc_o[4];
#pragma unroll
    for (int i = 0; i < 4; ++i) acc_o[i] = (f4){0.f, 0.f, 0.f, 0.f};
    float zr[4] = {0.f, 0.f, 0.f, 0.f};
    float acur[16], anxt[16];
    uint4 kr[2], vr[2];

    // prologue: stage tile 0, load its mask bytes
#pragma unroll
    for (int j = 0; j < 2; ++j) {
        int rl = w * 16 + j * 8 + (l >> 3);
        kr[j] = *(const uint4*)(kH + (size_t)rl * 128 + (l & 7) * 16);
        vr[j] = *(const uint4*)(vH + (size_t)rl * 4096 + (l & 7) * 16);
        *(uint4*)(Kb[0] + rl * 128 + (l & 7) * 16) = kr[j];
        *(uint4*)(Vb[0] + rl * 128 + (l & 7) * 16) = vr[j];
    }
#pragma unroll
    for (int nt = 0; nt < 4; ++nt)
#pragma unroll
        for (int r = 0; r < 4; ++r)
            acur[nt * 4 + r] =
                (float)A8[(size_t)(nt * 16 + c) * 2048 + dst0 + w * 16 + 4 * g + r];
    __syncthreads();

    for (int ts = 0; ts < 32; ++ts) {
        int cur = ts & 1;
        // issue next-tile global loads early (latency hides under MFMA/VALU)
        if (ts < 31) {
            int src0n = (ts + 1) * 64;
#pragma unroll
            for (int j = 0; j < 2; ++j) {
                int rl = w * 16 + j * 8 + (l >> 3);
                kr[j] = *(const uint4*)(kH + (size_t)(src0n + rl) * 128 + (l & 7) * 16);
                vr[j] = *(const uint4*)(vH + (size_t)rl * 4096 + (size_t)src0n * 2 + (l & 7) * 16);
            }
#pragma unroll
            for (int nt = 0; nt < 4; ++nt)
#pragma unroll
                for (int r = 0; r < 4; ++r)
                    anxt[nt * 4 + r] =
                        (float)A8[(size_t)(src0n + nt * 16 + c) * 2048 + dst0 + w * 16 + 4 * g + r];
        }

        // QK^T: M=dst(16/wave), N=src(64), K=dim(64)
        f4 as[4];
#pragma unroll
        for (int i = 0; i < 4; ++i) as[i] = (f4){0.f, 0.f, 0.f, 0.f};
#pragma unroll
        for (int nt = 0; nt < 4; ++nt) {
#pragma unroll
            for (int ch = 0; ch < 2; ++ch) {
                int rl = nt * 16 + c;
                h8 kf = *(const h8*)(Kb[cur] + rl * 128 + (((ch * 4 + g) ^ (rl & 7)) * 16));
                as[nt] = __builtin_amdgcn_mfma_f32_16x16x32_f16(qf[ch], kf, as[nt], 0, 0, 0);
            }
        }

        // exp + multiplicity mask + z + S->LDS (fp16)
#pragma unroll
        for (int nt = 0; nt < 4; ++nt) {
#pragma unroll
            for (int r = 0; r < 4; ++r) {
                float sc = fminf(fmaxf(as[nt][r], -CLAMP2), CLAMP2);
                float e = exp2f(sc) * acur[nt * 4 + r];
                zr[r] += e;
                uint p = pk2(e, e);
                int row = 4 * g + r, col = nt * 16 + c;
                *(ushort*)(Sw + row * 144 + (((col >> 3) ^ (row & 7)) * 16) + (col & 7) * 2) =
                    (ushort)p;
            }
        }

        // PV: M=dst, N=dim(64), K=src(64); S-frags from own LDS region
        h8 sf[2];
#pragma unroll
        for (int ch = 0; ch < 2; ++ch)
            sf[ch] = *(const h8*)(Sw + c * 144 + (((ch * 4 + g) ^ (c & 7)) * 16));
#pragma unroll
        for (int nt = 0; nt < 4; ++nt) {
#pragma unroll
            for (int ch = 0; ch < 2; ++ch) {
                int dl = nt * 16 + c;
                h8 vf = *(const h8*)(Vb[cur] + dl * 128 + (((ch * 4 + g) ^ (dl & 7)) * 16));
                acc_o[nt] = __builtin_amdgcn_mfma_f32_16x16x32_f16(sf[ch], vf, acc_o[nt], 0, 0, 0);
            }
        }

        // write next tile into the other LDS buffer, then barrier
        if (ts < 31) {
            int nb = (ts + 1) & 1;
#pragma unroll
            for (int j = 0; j < 2; ++j) {
                int rl = w * 16 + j * 8 + (l >> 3);
                *(uint4*)(Kb[nb] + rl * 128 + (l & 7) * 16) = kr[j];
                *(uint4*)(Vb[nb] + rl * 128 + (l & 7) * 16) = vr[j];
            }
#pragma unroll
            for (int i = 0; i < 16; ++i) acur[i] = anxt[i];
        }
        __syncthreads();
    }

    // z-reduce across the 16 lanes of each group (cols), then normalize + store
#pragma unroll
    for (int r = 0; r < 4; ++r) {
#pragma unroll
        for (int m = 1; m < 16; m <<= 1) zr[r] += __shfl_xor(zr[r], m);
        zr[r] = 1.0f / zr[r];
    }
#pragma unroll
    for (int nt = 0; nt < 4; ++nt)
#pragma unroll
        for (int r = 0; r < 4; ++r)
            out[(size_t)(dst0 + w * 16 + 4 * g + r) * 512 + h * 64 + nt * 16 + c] =
                acc_o[nt][r] * zr[r];
}

// ---------------- launch ----------------

extern "C" void kernel_launch(void* const* d_in, const int* in_sizes, int n_in,
                              void* d_out, int out_size, void* d_ws, size_t ws_size,
                              hipStream_t stream) {
    const float* q = (const float*)d_in[0];
    const float* k = (const float*)d_in[1];
    const float* v = (const float*)d_in[2];
    const int* esrc = (const int*)d_in[3];
    const int* edst = (const int*)d_in[4];
    float* out = (float*)d_out;
    const int E = in_sizes[3];

    uchar* A8 = (uchar*)d_ws;                               // 4MB  A^T[src][dst]
    ushort* kc = (ushort*)(A8 + (size_t)NNODES * NNODES);   // 2MB  fp16 [h][node][dim]
    ushort* vt = kc + (size_t)NHEAD * NNODES * DKDIM;       // 2MB  fp16 [h][dim][node]

    (void)hipMemsetAsync(A8, 0, (size_t)NNODES * NNODES, stream);
    conv_k<<<512, 256, 0, stream>>>(k, (uint4*)kc);
    conv_vT<<<256, 256, 0, stream>>>(v, vt);
    histA<<<E / 256, 256, 0, stream>>>(esrc, edst, (uint*)A8);
    attn_kernel<<<256, 256, 0, stream>>>(q, kc, vt, A8, out);
}

// Round 10
// 69.276 us; speedup vs baseline: 1.6848x; 1.6848x over previous
//
#include <hip/hip_runtime.h>

#define NNODES 2048
#define NHEAD 8
#define DKDIM 64

typedef unsigned int uint;
typedef unsigned short ushort;
typedef unsigned char uchar;
typedef __fp16 h2 __attribute__((ext_vector_type(2)));
typedef __fp16 h8 __attribute__((ext_vector_type(8)));
typedef float f4 __attribute__((ext_vector_type(4)));

#define KSCALE 0.18033688011112042f   // 0.125 * log2(e)
#define CLAMP2 14.426950408889634f    // 10 * log2(e)

__device__ __forceinline__ uint pk2(float a, float b) {
    union { h2 h; uint u; } x; x.h = __builtin_amdgcn_cvt_pkrtz(a, b); return x.u;
}

// ---- k -> fp16 [head][node][dim] (pre-scaled), linear; also zeroes A ----
__global__ void conv_k(const float* __restrict__ k, uint4* __restrict__ kc,
                       uint4* __restrict__ A4) {
    int i = blockIdx.x * 256 + threadIdx.x;      // 0..131071
    int dim8 = i & 7, node = (i >> 3) & 2047, h = i >> 14;
    const float* src = k + (size_t)node * 512 + h * 64 + dim8 * 8;
    float4 f0 = *(const float4*)src;
    float4 f1 = *(const float4*)(src + 4);
    uint4 o;
    o.x = pk2(f0.x * KSCALE, f0.y * KSCALE);
    o.y = pk2(f0.z * KSCALE, f0.w * KSCALE);
    o.z = pk2(f1.x * KSCALE, f1.y * KSCALE);
    o.w = pk2(f1.z * KSCALE, f1.w * KSCALE);
    kc[(h * 2048 + node) * 8 + dim8] = o;
    uint4 zz = {0u, 0u, 0u, 0u};
    A4[i] = zz;
    A4[i + 131072] = zz;
}

// ---- v -> fp16 transposed [head][dim][node], linear ----
__global__ void conv_vT(const float* __restrict__ v, ushort* __restrict__ vt) {
    __shared__ float tile[64][65];
    int b = blockIdx.x;        // 256 = 8 heads * 32 node-tiles
    int h = b & 7, tn = b >> 3;
    int t = threadIdx.x;
    int nl = t >> 2, dq = (t & 3) * 16;
    const float* src = v + ((size_t)(tn * 64 + nl)) * 512 + h * 64 + dq;
#pragma unroll
    for (int i = 0; i < 4; ++i) {
        float4 f = *(const float4*)(src + i * 4);
        tile[nl][dq + i * 4 + 0] = f.x;
        tile[nl][dq + i * 4 + 1] = f.y;
        tile[nl][dq + i * 4 + 2] = f.z;
        tile[nl][dq + i * 4 + 3] = f.w;
    }
    __syncthreads();
    int dim = t >> 2, nq = (t & 3) * 16;
    uint wv[8];
#pragma unroll
    for (int i = 0; i < 8; ++i)
        wv[i] = pk2(tile[nq + 2 * i][dim], tile[nq + 2 * i + 1][dim]);
    char* base = (char*)vt + ((size_t)(h * 64 + dim) * 2048 + tn * 64) * 2;
    int nb0 = (t & 3) * 2;
    uint4 lo = { wv[0], wv[1], wv[2], wv[3] };
    uint4 hi = { wv[4], wv[5], wv[6], wv[7] };
    *(uint4*)(base + nb0 * 16) = lo;
    *(uint4*)(base + nb0 * 16 + 16) = hi;
}

// ---- multiplicity matrix A^T[src][dst] u8, packed-byte atomics ----
__global__ void histA(const int* __restrict__ es, const int* __restrict__ ed,
                      uint* __restrict__ A32, int E) {
    int i = blockIdx.x * 256 + threadIdx.x;
    if (i < E) {
        uint idx = (uint)es[i] * 2048u + (uint)ed[i];
        atomicAdd(&A32[idx >> 2], 1u << ((idx & 3) * 8));
    }
}

// ---- dense masked attention ----
// Block = 64 dst rows x 1 head, 512 threads = 8 waves.
// half = w>>2 owns src tiles [half*16, half*16+16); wq = w&3 owns dst strip.
// Swapped MFMAs: QK^T = mfma(K,Q) -> lane col = dst; PV = mfma(V^T,S).
// A-mask LDS-staged per tile via coalesced uint4; S per-wave LDS round trip.
__global__ void __launch_bounds__(512, 1) attn_kernel(
    const float* __restrict__ q, const ushort* __restrict__ kc, const ushort* __restrict__ vt,
    const uchar* __restrict__ A8, float* __restrict__ out) {
    __shared__ __align__(16) char LK[2][2][8192];   // [half][buf][64 src x 128B]
    __shared__ __align__(16) char LV[2][2][8192];   // [half][buf][64 dim x 128B]
    __shared__ __align__(16) char LA[2][2][4096];   // [half][buf][64 src x 64 dst]
    __shared__ __align__(16) char LS[8][2304];      // per-wave S [16 dst][144B]

    int b = blockIdx.x;
    int h = b & 7;
    int dst0 = (b >> 3) * 64;
    int t = threadIdx.x;
    int w = t >> 6, half = w >> 2, wq = w & 3;
    int l = t & 63, c = l & 15, g = l >> 4;
    int ht = t & 255;

    const char* kH = (const char*)kc + (size_t)h * 262144;
    const char* vH = (const char*)vt + (size_t)h * 262144;

    // Q fragments: lane holds Q[dst = dst0+wq*16+c][dim = ch*32+8g .. +7]
    h8 qf[2];
    {
        const float* qp = q + (size_t)(dst0 + wq * 16 + c) * 512 + h * 64 + g * 8;
#pragma unroll
        for (int ch = 0; ch < 2; ++ch) {
            float4 f0 = *(const float4*)(qp + ch * 32);
            float4 f1 = *(const float4*)(qp + ch * 32 + 4);
            union { uint u[4]; h8 v; } U;
            U.u[0] = pk2(f0.x, f0.y); U.u[1] = pk2(f0.z, f0.w);
            U.u[2] = pk2(f1.x, f1.y); U.u[3] = pk2(f1.z, f1.w);
            qf[ch] = U.v;
        }
    }

    f4 of[4];
#pragma unroll
    for (int i = 0; i < 4; ++i) of[i] = (f4){0.f, 0.f, 0.f, 0.f};
    float z = 0.f;

    int r0 = ht >> 3, b0 = ht & 7;     // K/V staging: row, 16B-block
    int ar_ = ht >> 2, as_ = ht & 3;   // A staging: row, 16B-seg
    uint4 kr[2], vr[2], ar;
    int ts0 = half * 16;

    // prologue: stage tile ts0 into buf 0
#pragma unroll
    for (int j = 0; j < 2; ++j) {
        int row = r0 + j * 32;
        kr[j] = *(const uint4*)(kH + (size_t)(ts0 * 64 + row) * 128 + b0 * 16);
        vr[j] = *(const uint4*)(vH + (size_t)row * 4096 + ts0 * 128 + b0 * 16);
        *(uint4*)(LK[half][0] + row * 128 + b0 * 16) = kr[j];
        *(uint4*)(LV[half][0] + row * 128 + b0 * 16) = vr[j];
    }
    ar = *(const uint4*)(A8 + (size_t)(ts0 * 64 + ar_) * 2048 + dst0 + as_ * 16);
    *(uint4*)(LA[half][0] + ar_ * 64 + as_ * 16) = ar;
    __syncthreads();

    for (int it = 0; it < 16; ++it) {
        int cur = it & 1;
        int ts = ts0 + it;
        // issue next-tile loads early (hide HBM/L2 latency under compute)
        if (it < 15) {
#pragma unroll
            for (int j = 0; j < 2; ++j) {
                int row = r0 + j * 32;
                kr[j] = *(const uint4*)(kH + (size_t)((ts + 1) * 64 + row) * 128 + b0 * 16);
                vr[j] = *(const uint4*)(vH + (size_t)row * 4096 + (ts + 1) * 128 + b0 * 16);
            }
            ar = *(const uint4*)(A8 + (size_t)((ts + 1) * 64 + ar_) * 2048 + dst0 + as_ * 16);
        }

        // QK^T swapped: sacc[nt] lane holds S[dst=c][src = nt*16+4g+r]
        f4 sacc[4];
#pragma unroll
        for (int i = 0; i < 4; ++i) sacc[i] = (f4){0.f, 0.f, 0.f, 0.f};
#pragma unroll
        for (int nt = 0; nt < 4; ++nt)
#pragma unroll
            for (int ch = 0; ch < 2; ++ch) {
                h8 kf = *(const h8*)(LK[half][cur] + (nt * 16 + c) * 128 + (ch * 4 + g) * 16);
                sacc[nt] = __builtin_amdgcn_mfma_f32_16x16x32_f16(kf, qf[ch], sacc[nt], 0, 0, 0);
            }

        // exp + multiplicity mask + z; S -> per-wave LDS [dst][src]
        char* Sw = LS[w];
        const uchar* Ac = (const uchar*)LA[half][cur];
#pragma unroll
        for (int nt = 0; nt < 4; ++nt)
#pragma unroll
            for (int r = 0; r < 4; ++r) {
                float sc = fminf(fmaxf(sacc[nt][r], -CLAMP2), CLAMP2);
                float m = (float)Ac[(nt * 16 + 4 * g + r) * 64 + wq * 16 + c];
                float e = exp2f(sc) * m;
                z += e;
                *(ushort*)(Sw + c * 144 + (nt * 16 + 4 * g + r) * 2) = (ushort)pk2(e, e);
            }
        asm volatile("" ::: "memory");   // keep S writes before S reads

        // PV swapped: of[nt] lane holds O[dst=c][dim = nt*16+4g+r]
        h8 sf[2];
#pragma unroll
        for (int ch = 0; ch < 2; ++ch)
            sf[ch] = *(const h8*)(Sw + c * 144 + (ch * 32 + 8 * g) * 2);
#pragma unroll
        for (int nt = 0; nt < 4; ++nt)
#pragma unroll
            for (int ch = 0; ch < 2; ++ch) {
                h8 vf = *(const h8*)(LV[half][cur] + (nt * 16 + c) * 128 + (ch * 4 + g) * 16);
                of[nt] = __builtin_amdgcn_mfma_f32_16x16x32_f16(vf, sf[ch], of[nt], 0, 0, 0);
            }

        // write next tile into the other buffer
        if (it < 15) {
            int nb = cur ^ 1;
#pragma unroll
            for (int j = 0; j < 2; ++j) {
                int row = r0 + j * 32;
                *(uint4*)(LK[half][nb] + row * 128 + b0 * 16) = kr[j];
                *(uint4*)(LV[half][nb] + row * 128 + b0 * 16) = vr[j];
            }
            *(uint4*)(LA[half][nb] + ar_ * 64 + as_ * 16) = ar;
        }
        __syncthreads();
    }

    // z: reduce across the 4 g-lanes of each dst column
    z += __shfl_xor(z, 16);
    z += __shfl_xor(z, 32);

    // combine halves + normalize via LDS (reuse LK/LV space)
    float* CL = (float*)&LK[0][0][0];    // [64 rows][65] f32
    float* CLz = (float*)&LV[0][0][0];   // [64]
    if (half == 1) {
#pragma unroll
        for (int nt = 0; nt < 4; ++nt)
#pragma unroll
            for (int r = 0; r < 4; ++r)
                CL[(wq * 16 + c) * 65 + nt * 16 + 4 * g + r] = of[nt][r];
        if (l < 16) CLz[wq * 16 + c] = z;
    }
    __syncthreads();
    if (half == 0) {
        float zt = 1.0f / (z + CLz[wq * 16 + c]);
#pragma unroll
        for (int nt = 0; nt < 4; ++nt)
#pragma unroll
            for (int r = 0; r < 4; ++r) {
                int idx = (wq * 16 + c) * 65 + nt * 16 + 4 * g + r;
                CL[idx] = (of[nt][r] + CL[idx]) * zt;
            }
    }
    __syncthreads();
    // coalesced store: wave w writes rows w*8 .. w*8+7, lane = dim
#pragma unroll
    for (int j = 0; j < 8; ++j) {
        int i2 = w * 8 + j;
        out[(size_t)(dst0 + i2) * 512 + h * 64 + l] = CL[i2 * 65 + l];
    }
}

// ---------------- launch ----------------

extern "C" void kernel_launch(void* const* d_in, const int* in_sizes, int n_in,
                              void* d_out, int out_size, void* d_ws, size_t ws_size,
                              hipStream_t stream) {
    const float* q = (const float*)d_in[0];
    const float* k = (const float*)d_in[1];
    const float* v = (const float*)d_in[2];
    const int* esrc = (const int*)d_in[3];
    const int* edst = (const int*)d_in[4];
    float* out = (float*)d_out;
    const int E = in_sizes[3];

    uchar* A8 = (uchar*)d_ws;                               // 4MB  A^T[src][dst]
    ushort* kc = (ushort*)(A8 + (size_t)NNODES * NNODES);   // 2MB  fp16 [h][node][dim]
    ushort* vt = kc + (size_t)NHEAD * NNODES * DKDIM;       // 2MB  fp16 [h][dim][node]

    conv_k<<<512, 256, 0, stream>>>(k, (uint4*)kc, (uint4*)A8);
    conv_vT<<<256, 256, 0, stream>>>(v, vt);
    histA<<<(E + 255) / 256, 256, 0, stream>>>(esrc, edst, (uint*)A8, E);
    attn_kernel<<<256, 512, 0, stream>>>(q, kc, vt, A8, out);
}